// Round 17
// baseline (40.743 us; speedup 1.0000x reference)
//
#include <hip/hip_runtime.h>
#include <hip/hip_bf16.h>

// Problem constants (B=8, S=4096, D=128 per reference setup_inputs)
#define B_ 8
#define S_ 4096
#define D_ 128
#define C_ 256                 // chunk length
#define NC 16                  // chunks per batch = S_/C_

typedef __attribute__((ext_vector_type(8))) short bf16x8;   // MFMA A/B frag (4 VGPRs)
typedef __attribute__((ext_vector_type(4))) float f32x4;    // 16x16 MFMA C/D frag
typedef __attribute__((ext_vector_type(4))) unsigned u32x4;

// f32 -> bf16 round-to-nearest-even
static __device__ __forceinline__ unsigned short f2bf(float x) {
    unsigned u = __float_as_uint(x);
    u += 0x7fffu + ((u >> 16) & 1u);
    return (unsigned short)(u >> 16);
}

// async global -> LDS, 16 bytes per lane (dest = wave-uniform base + lane*16)
typedef const __attribute__((address_space(1))) unsigned int* gas_ptr;
typedef __attribute__((address_space(3))) unsigned int* las_ptr;
static __device__ __forceinline__ void load_lds16(const unsigned short* g, unsigned short* l) {
    __builtin_amdgcn_global_load_lds((gas_ptr)(const void*)g, (las_ptr)(void*)l, 16, 0, 0);
}

#define WAIT_VMCNT_8 do { asm volatile("s_waitcnt vmcnt(8)" ::: "memory"); \
                          __builtin_amdgcn_sched_barrier(0); } while (0)
#define WAIT_VMCNT_0 do { asm volatile("s_waitcnt vmcnt(0)" ::: "memory"); \
                          __builtin_amdgcn_sched_barrier(0); } while (0)
#define BARRIER      do { __builtin_amdgcn_s_barrier(); \
                          __builtin_amdgcn_sched_barrier(0); } while (0)

// ---------------------------------------------------------------------------
// fusedA (512 threads, 8 waves — r17: occupancy fix, logic identical to r16):
//   per (b, chunk, t-half of 128): read K,V f32; RoPE K in-register; write Kr;
//   scatter transposed bf16 K/V into XOR-swizzled LDS (cc ^ (row&15));
//   write Vt [B][D][S] from LDS; compute G half-partial
//   P1[b][c][half][dp][d] = sum_t V[t][dp] K[t][d] via MFMA from LDS.
//   Wave w owns dp rows [16w, 16w+16) -> acc[8], 32 VGPRs.
// MFMA 16x16x32 bf16 layouts (verified rounds 1-16):
//   A: lane l holds A[row=l&15][k=8*(l>>4)+j]; B: B[k=8*(l>>4)+j][col=l&15]
//   C/D: lane,reg holds D[row=4*(l>>4)+reg][col=l&15]
// ---------------------------------------------------------------------------
__global__ __launch_bounds__(512, 2) void fusedA(const float* __restrict__ K,
                                                 const float* __restrict__ V,
                                                 unsigned short* __restrict__ Kr,
                                                 unsigned short* __restrict__ Vt,
                                                 float* __restrict__ P1) {
    __shared__ unsigned short Klds[128 * 128];    // [d][t-half] swizzled chunks, 32KB
    __shared__ unsigned short Vlds[128 * 128];    // same, 32KB

    const int b    = blockIdx.x >> 5;
    const int c    = (blockIdx.x >> 1) & 15;
    const int half = blockIdx.x & 1;
    const int tid  = threadIdx.x;
    const int t0   = c * C_ + half * 128;         // global t base of this half

    // ---- load f32, RoPE K, write Kr, scatter transposed bf16 to LDS ----
    #pragma unroll
    for (int it = 0; it < 4; ++it) {
        int e  = it * 512 + tid;
        int tl = e >> 4;                          // 0..127 local t
        int d0 = (e & 15) * 4;                    // 0..60 (pairs with d0+64)
        size_t gbase = ((size_t)(b * S_ + t0 + tl)) * D_;
        float ka[4], kb[4], va[4], vb[4];
        *(float4*)ka = *(const float4*)(K + gbase + d0);
        *(float4*)kb = *(const float4*)(K + gbase + d0 + 64);
        *(float4*)va = *(const float4*)(V + gbase + d0);
        *(float4*)vb = *(const float4*)(V + gbase + d0 + 64);
        unsigned short kl[4], kh[4];
        #pragma unroll
        for (int jj = 0; jj < 4; ++jj) {
            float invf = exp2f(-0.20762050f * (float)(d0 + jj));  // 10000^{-d/64}
            float ang = (float)(t0 + tl) * invf;
            float sn, cs;
            __sincosf(ang, &sn, &cs);
            kl[jj] = f2bf(ka[jj] * cs - kb[jj] * sn);
            kh[jj] = f2bf(kb[jj] * cs + ka[jj] * sn);
        }
        *reinterpret_cast<ushort4*>(Kr + gbase + d0)      = ushort4{kl[0], kl[1], kl[2], kl[3]};
        *reinterpret_cast<ushort4*>(Kr + gbase + d0 + 64) = ushort4{kh[0], kh[1], kh[2], kh[3]};
        int cc = tl >> 3, tr = tl & 7;            // 16B chunk + offset within
        #pragma unroll
        for (int jj = 0; jj < 4; ++jj) {
            int dA = d0 + jj, dB = d0 + 64 + jj;
            Klds[dA * 128 + ((cc ^ (dA & 15)) * 8) + tr] = kl[jj];
            Klds[dB * 128 + ((cc ^ (dB & 15)) * 8) + tr] = kh[jj];
            Vlds[dA * 128 + ((cc ^ (dA & 15)) * 8) + tr] = f2bf(va[jj]);
            Vlds[dB * 128 + ((cc ^ (dB & 15)) * 8) + tr] = f2bf(vb[jj]);
        }
    }
    __syncthreads();

    // ---- write Vt [B][D][S] from LDS (coalesced 16B chunks along t) ----
    #pragma unroll
    for (int it = 0; it < 4; ++it) {
        int e = it * 512 + tid;
        int d = e >> 4;                           // 0..127
        int cc = e & 15;
        const bf16x8 v8 = *reinterpret_cast<const bf16x8*>(
            &Vlds[d * 128 + ((cc ^ (d & 15)) * 8)]);
        *reinterpret_cast<bf16x8*>(
            Vt + ((size_t)(b * D_ + d)) * S_ + t0 + cc * 8) = v8;
    }

    // ---- G half-partial: D[dp][d] = sum_t V[t][dp] K[t][d], t over 128 ----
    const int w = tid >> 6, l = tid & 63, g = l >> 4, n = l & 15;
    f32x4 acc[8];
    #pragma unroll
    for (int dc = 0; dc < 8; ++dc) acc[dc] = f32x4{0.f, 0.f, 0.f, 0.f};

    #pragma unroll
    for (int ki = 0; ki < 4; ++ki) {
        const int arow = 16 * w + n;              // wave's dp rows; row&15 == n
        const bf16x8 a = *reinterpret_cast<const bf16x8*>(
            &Vlds[arow * 128 + (((4 * ki + g) ^ n) * 8)]);
        #pragma unroll
        for (int dc = 0; dc < 8; ++dc) {
            int row = dc * 16 + n;
            const bf16x8 bb = *reinterpret_cast<const bf16x8*>(
                &Klds[row * 128 + (((4 * ki + g) ^ n) * 8)]);
            acc[dc] = __builtin_amdgcn_mfma_f32_16x16x32_bf16(a, bb, acc[dc], 0, 0, 0);
        }
    }

    float* out = P1 + (size_t)((b * NC + c) * 2 + half) * D_ * D_;
    #pragma unroll
    for (int dc = 0; dc < 8; ++dc)
        #pragma unroll
        for (int rr = 0; rr < 4; ++rr)
            out[(size_t)(16 * w + 4 * g + rr) * D_ + dc * 16 + n] = acc[dc][rr];
}

// ---------------------------------------------------------------------------
// prefix: exclusive prefix over chunk partials (2 halves each); single bf16 H.
//   thread -> (b,dp,d), d = gid&127 -> all reads/writes coalesced.
// ---------------------------------------------------------------------------
__global__ __launch_bounds__(256) void prefix(const float* __restrict__ P1,
                                              unsigned short* __restrict__ Hhi) {
    int gid = blockIdx.x * 256 + threadIdx.x;     // 0 .. 131071
    int d  = gid & 127;
    int dp = (gid >> 7) & 127;
    int b  = gid >> 14;
    float run = 0.f;
    #pragma unroll
    for (int c = 0; c < NC; ++c) {
        size_t hidx = ((size_t)(b * NC + c) * D_ + dp) * D_ + d;
        Hhi[hidx] = f2bf(run);
        size_t p = ((size_t)((b * NC + c) * 2) * D_ + dp) * D_ + d;
        run += P1[p];
        run += P1[p + (size_t)D_ * D_];
    }
}

// ---------------------------------------------------------------------------
// pass2: O_c = Qr_c . H_c (inter)  +  causal(Qr_c.Kr_c^T).V_c (intra).
//   Q RoPE'd in-register from f32. 512 blocks = 4 pp-groups (perm {3,2,0,1})
//   x 128 (b,c); 4 waves x 16 rows. Intra: K/V double-buffered (64KB),
//   counted-vmcnt skeleton. Unchanged from rounds 15/16 (passing).
// ---------------------------------------------------------------------------
__global__ __launch_bounds__(256, 2) void pass2(const float* __restrict__ Q,
                                                const unsigned short* __restrict__ Kr,
                                                const unsigned short* __restrict__ Vt,
                                                const unsigned short* __restrict__ Hhi,
                                                float* __restrict__ Out) {
    __shared__ unsigned short Kb[2][64 * 128];    // [t][d] swizzled chunks, 2x16KB
    __shared__ unsigned short Vb[2][128 * 64];    // [d][t] swizzled chunks, 2x16KB

    const int bid = blockIdx.x;
    const int ppmap[4] = {3, 2, 0, 1};
    const int pp = ppmap[bid >> 7];               // q-64-tile within chunk
    const int r2 = bid & 127;
    const int b  = r2 & 7;
    const int c  = r2 >> 3;                       // chunk 0..15
    const int qg = c * 4 + pp;
    const int c4 = c * 4;

    const int tid = threadIdx.x;
    const int wv = tid >> 6;
    const int l  = tid & 63;
    const int g  = l >> 4;
    const int n  = l & 15;

    // ---- hoist Q with in-register RoPE: lane holds Q[s][d=32ks+8g+j] ----
    bf16x8 qf[4];
    {
        const int s = qg * 64 + wv * 16 + n;
        const float* qp = Q + ((size_t)(b * S_ + s)) * D_ + 8 * g;
        float qv[4][8];
        #pragma unroll
        for (int ks = 0; ks < 4; ++ks) {
            *reinterpret_cast<float4*>(&qv[ks][0]) =
                *reinterpret_cast<const float4*>(qp + 32 * ks);
            *reinterpret_cast<float4*>(&qv[ks][4]) =
                *reinterpret_cast<const float4*>(qp + 32 * ks + 4);
        }
        unsigned short qb[4][8];
        #pragma unroll
        for (int hf = 0; hf < 2; ++hf)
            #pragma unroll
            for (int j = 0; j < 8; ++j) {
                int dm = 32 * hf + 8 * g + j;     // d mod 64
                float invf = exp2f(-0.20762050f * (float)dm);
                float ang = (float)s * invf;
                float sn, cs;
                __sincosf(ang, &sn, &cs);
                qb[hf][j]     = f2bf(qv[hf][j] * cs - qv[hf + 2][j] * sn);
                qb[hf + 2][j] = f2bf(qv[hf + 2][j] * cs + qv[hf][j] * sn);
            }
        #pragma unroll
        for (int ks = 0; ks < 4; ++ks) {
            bf16x8 f;
            #pragma unroll
            for (int j = 0; j < 8; ++j) f[j] = (short)qb[ks][j];
            qf[ks] = f;
        }
    }

    // K LDS chunk (t,cc) <- global chunk (t, cc^(t&15)); V chunk (d,cc) <- cc^(d&7)
    auto stage = [&](int bufs, int tg) {
        const unsigned short* kbase = Kr + ((size_t)(b * S_ + tg * 64)) * D_;
        #pragma unroll
        for (int i = 0; i < 4; ++i) {
            int ci = i * 256 + tid;
            int t = ci >> 4, cc = ci & 15;
            load_lds16(kbase + t * D_ + ((cc ^ (t & 15)) * 8), &Kb[bufs][ci * 8]);
        }
        const unsigned short* vbase = Vt + (size_t)b * D_ * S_ + (size_t)tg * 64;
        #pragma unroll
        for (int i = 0; i < 4; ++i) {
            int ci = i * 256 + tid;
            int d = ci >> 3, cc = ci & 7;
            load_lds16(vbase + (size_t)d * S_ + ((cc ^ (d & 7)) * 8), &Vb[bufs][ci * 8]);
        }
    };

    f32x4 o[8];
    #pragma unroll
    for (int df = 0; df < 8; ++df) o[df] = f32x4{0.f, 0.f, 0.f, 0.f};

    stage(0, c4);                                  // tile 0 (8 vm entries)
    if (pp >= 1) stage(1, c4 + 1);                 // tile 1 (8 more)

    // ---- inter: O += Q . H (single bf16 H); DMAs fly underneath ----
    {
        const unsigned short* hbase = Hhi + (size_t)(b * NC + c) * D_ * D_;
        #pragma unroll
        for (int ks = 0; ks < 4; ++ks) {
            #pragma unroll
            for (int df = 0; df < 8; ++df) {
                const bf16x8 hh = *reinterpret_cast<const bf16x8*>(
                    hbase + (size_t)(df * 16 + n) * D_ + 32 * ks + 8 * g);
                o[df] = __builtin_amdgcn_mfma_f32_16x16x32_bf16(qf[ks], hh, o[df], 0, 0, 0);
            }
        }
    }

    // ---- intra: kt = 0..pp causal tiles, double-buffered counted-vmcnt ----
    for (int kt = 0; kt <= pp; ++kt) {
        if (kt < pp) { WAIT_VMCNT_8; }             // tile kt landed; kt+1 in flight
        else         { WAIT_VMCNT_0; }
        BARRIER;

        const int bufc = kt & 1;

        // E^T = K.Q^T (swapped): lane(g,n) holds E[t=tf*16+4g+rr][s=qg*64+wv*16+n]
        f32x4 e[4];
        #pragma unroll
        for (int tf = 0; tf < 4; ++tf) e[tf] = f32x4{0.f, 0.f, 0.f, 0.f};
        __builtin_amdgcn_s_setprio(1);
        #pragma unroll
        for (int tf = 0; tf < 4; ++tf) {
            #pragma unroll
            for (int ks = 0; ks < 4; ++ks) {
                const bf16x8 kf = *reinterpret_cast<const bf16x8*>(
                    &Kb[bufc][(tf * 16 + n) * 128 + (((4 * ks + g) ^ n) * 8)]);
                e[tf] = __builtin_amdgcn_mfma_f32_16x16x32_bf16(kf, qf[ks], e[tf], 0, 0, 0);
            }
        }
        __builtin_amdgcn_s_setprio(0);

        if (kt == pp) {                            // diagonal tile: causal mask
            int s_glob = qg * 64 + wv * 16 + n;
            #pragma unroll
            for (int tf = 0; tf < 4; ++tf)
                #pragma unroll
                for (int rr = 0; rr < 4; ++rr) {
                    int t_glob = (c4 + kt) * 64 + tf * 16 + 4 * g + rr;
                    if (t_glob > s_glob) e[tf][rr] = 0.f;
                }
        }

        // E -> P A-frags in-register (8 cvt_pk + 8 permlane swaps, r4-verified)
        bf16x8 pf[2];
        {
            unsigned u0[4], u1[4];
            #pragma unroll
            for (int tf = 0; tf < 4; ++tf) {
                asm("v_cvt_pk_bf16_f32 %0, %1, %2"
                    : "=v"(u0[tf]) : "v"(e[tf][0]), "v"(e[tf][1]));
                asm("v_cvt_pk_bf16_f32 %0, %1, %2"
                    : "=v"(u1[tf]) : "v"(e[tf][2]), "v"(e[tf][3]));
            }
            #pragma unroll
            for (int ks = 0; ks < 2; ++ks) {
                unsigned a0 = u0[2 * ks], a1 = u0[2 * ks + 1];
                unsigned b0 = u1[2 * ks], b1 = u1[2 * ks + 1];
                asm("v_permlane32_swap_b32 %0, %1" : "+v"(a0), "+v"(a1));
                asm("v_permlane32_swap_b32 %0, %1" : "+v"(b0), "+v"(b1));
                asm("v_permlane16_swap_b32 %0, %1" : "+v"(a0), "+v"(a1));
                asm("v_permlane16_swap_b32 %0, %1" : "+v"(b0), "+v"(b1));
                pf[ks] = __builtin_bit_cast(bf16x8, u32x4{a0, b0, a1, b1});
            }
        }

        // O += P.V
        __builtin_amdgcn_s_setprio(1);
        #pragma unroll
        for (int df = 0; df < 8; ++df) {
            #pragma unroll
            for (int ks = 0; ks < 2; ++ks) {
                const bf16x8 vf = *reinterpret_cast<const bf16x8*>(
                    &Vb[bufc][(df * 16 + n) * 64 + (((4 * ks + g) ^ (n & 7)) * 8)]);
                o[df] = __builtin_amdgcn_mfma_f32_16x16x32_bf16(pf[ks], vf, o[df], 0, 0, 0);
            }
        }
        __builtin_amdgcn_s_setprio(0);

        BARRIER;                                   // all waves done reading bufc

        if (kt + 2 <= pp) stage(bufc, c4 + kt + 2);
    }

    // ---- epilogue: exclusive rows -> plain stores ----
    #pragma unroll
    for (int df = 0; df < 8; ++df)
        #pragma unroll
        for (int rr = 0; rr < 4; ++rr) {
            int srow = qg * 64 + wv * 16 + 4 * g + rr;
            Out[((size_t)(b * S_ + srow)) * D_ + df * 16 + n] = o[df][rr];
        }
}

// ---------------------------------------------------------------------------
extern "C" void kernel_launch(void* const* d_in, const int* in_sizes, int n_in,
                              void* d_out, int out_size, void* d_ws, size_t ws_size,
                              hipStream_t stream) {
    const float* Q = (const float*)d_in[0];
    const float* K = (const float*)d_in[1];
    const float* V = (const float*)d_in[2];

    const size_t NE = (size_t)B_ * S_ * D_;       // 4.19M elems
    unsigned short* Kr = (unsigned short*)d_ws;                    // 8 MB
    unsigned short* Vt = Kr + NE;                                  // 8 MB
    float*          P1 = (float*)(Vt + NE);                        // 16 MB f32 (2 halves)
    unsigned short* Hhi = (unsigned short*)(P1 + (size_t)B_ * NC * 2 * D_ * D_); // 4 MB

    fusedA<<<256, 512, 0, stream>>>(K, V, Kr, Vt, P1);
    prefix<<<512, 256, 0, stream>>>(P1, Hhi);
    pass2 <<<512, 256, 0, stream>>>(Q, Kr, Vt, Hhi, (float*)d_out);
}

// Round 18
// 39.774 us; speedup vs baseline: 1.0244x; 1.0244x over previous
//
#include <hip/hip_runtime.h>
#include <hip/hip_bf16.h>

// Problem constants (B=8, S=4096, D=128 per reference setup_inputs)
#define B_ 8
#define S_ 4096
#define D_ 128
#define C_ 256                 // chunk length
#define NC 16                  // chunks per batch = S_/C_

typedef __attribute__((ext_vector_type(8))) short bf16x8;   // MFMA A/B frag (4 VGPRs)
typedef __attribute__((ext_vector_type(4))) float f32x4;    // 16x16 MFMA C/D frag
typedef __attribute__((ext_vector_type(4))) unsigned u32x4;

// f32 -> bf16 round-to-nearest-even
static __device__ __forceinline__ unsigned short f2bf(float x) {
    unsigned u = __float_as_uint(x);
    u += 0x7fffu + ((u >> 16) & 1u);
    return (unsigned short)(u >> 16);
}
static __device__ __forceinline__ float bf2f(unsigned short h) {
    return __uint_as_float(((unsigned)h) << 16);
}

// async global -> LDS, 16 bytes per lane (dest = wave-uniform base + lane*16)
typedef const __attribute__((address_space(1))) unsigned int* gas_ptr;
typedef __attribute__((address_space(3))) unsigned int* las_ptr;
static __device__ __forceinline__ void load_lds16(const unsigned short* g, unsigned short* l) {
    __builtin_amdgcn_global_load_lds((gas_ptr)(const void*)g, (las_ptr)(void*)l, 16, 0, 0);
}

#define WAIT_VMCNT_4 do { asm volatile("s_waitcnt vmcnt(4)" ::: "memory"); \
                          __builtin_amdgcn_sched_barrier(0); } while (0)
#define WAIT_VMCNT_0 do { asm volatile("s_waitcnt vmcnt(0)" ::: "memory"); \
                          __builtin_amdgcn_sched_barrier(0); } while (0)
#define BARRIER      do { __builtin_amdgcn_s_barrier(); \
                          __builtin_amdgcn_sched_barrier(0); } while (0)

// ---------------------------------------------------------------------------
// fusedA (512 threads, 8 waves; r18: P1 stored bf16):
//   per (b, chunk, t-half of 128): read K,V f32; RoPE K in-register; write Kr;
//   scatter transposed bf16 K/V into XOR-swizzled LDS (cc ^ (row&15));
//   write Vt [B][D][S] from LDS; compute G half-partial
//   P1[b][c][half][dp][d] = sum_t V[t][dp] K[t][d] via MFMA from LDS -> bf16.
// MFMA 16x16x32 bf16 layouts (verified rounds 1-17):
//   A: lane l holds A[row=l&15][k=8*(l>>4)+j]; B: B[k=8*(l>>4)+j][col=l&15]
//   C/D: lane,reg holds D[row=4*(l>>4)+reg][col=l&15]
// ---------------------------------------------------------------------------
__global__ __launch_bounds__(512, 2) void fusedA(const float* __restrict__ K,
                                                 const float* __restrict__ V,
                                                 unsigned short* __restrict__ Kr,
                                                 unsigned short* __restrict__ Vt,
                                                 unsigned short* __restrict__ P1h) {
    __shared__ unsigned short Klds[128 * 128];    // [d][t-half] swizzled chunks, 32KB
    __shared__ unsigned short Vlds[128 * 128];    // same, 32KB

    const int b    = blockIdx.x >> 5;
    const int c    = (blockIdx.x >> 1) & 15;
    const int half = blockIdx.x & 1;
    const int tid  = threadIdx.x;
    const int t0   = c * C_ + half * 128;         // global t base of this half

    // ---- load f32, RoPE K, write Kr, scatter transposed bf16 to LDS ----
    #pragma unroll
    for (int it = 0; it < 4; ++it) {
        int e  = it * 512 + tid;
        int tl = e >> 4;                          // 0..127 local t
        int d0 = (e & 15) * 4;                    // 0..60 (pairs with d0+64)
        size_t gbase = ((size_t)(b * S_ + t0 + tl)) * D_;
        float ka[4], kb[4], va[4], vb[4];
        *(float4*)ka = *(const float4*)(K + gbase + d0);
        *(float4*)kb = *(const float4*)(K + gbase + d0 + 64);
        *(float4*)va = *(const float4*)(V + gbase + d0);
        *(float4*)vb = *(const float4*)(V + gbase + d0 + 64);
        unsigned short kl[4], kh[4];
        #pragma unroll
        for (int jj = 0; jj < 4; ++jj) {
            float invf = exp2f(-0.20762050f * (float)(d0 + jj));  // 10000^{-d/64}
            float ang = (float)(t0 + tl) * invf;
            float sn, cs;
            __sincosf(ang, &sn, &cs);
            kl[jj] = f2bf(ka[jj] * cs - kb[jj] * sn);
            kh[jj] = f2bf(kb[jj] * cs + ka[jj] * sn);
        }
        *reinterpret_cast<ushort4*>(Kr + gbase + d0)      = ushort4{kl[0], kl[1], kl[2], kl[3]};
        *reinterpret_cast<ushort4*>(Kr + gbase + d0 + 64) = ushort4{kh[0], kh[1], kh[2], kh[3]};
        int cc = tl >> 3, tr = tl & 7;            // 16B chunk + offset within
        #pragma unroll
        for (int jj = 0; jj < 4; ++jj) {
            int dA = d0 + jj, dB = d0 + 64 + jj;
            Klds[dA * 128 + ((cc ^ (dA & 15)) * 8) + tr] = kl[jj];
            Klds[dB * 128 + ((cc ^ (dB & 15)) * 8) + tr] = kh[jj];
            Vlds[dA * 128 + ((cc ^ (dA & 15)) * 8) + tr] = f2bf(va[jj]);
            Vlds[dB * 128 + ((cc ^ (dB & 15)) * 8) + tr] = f2bf(vb[jj]);
        }
    }
    __syncthreads();

    // ---- write Vt [B][D][S] from LDS (coalesced 16B chunks along t) ----
    #pragma unroll
    for (int it = 0; it < 4; ++it) {
        int e = it * 512 + tid;
        int d = e >> 4;                           // 0..127
        int cc = e & 15;
        const bf16x8 v8 = *reinterpret_cast<const bf16x8*>(
            &Vlds[d * 128 + ((cc ^ (d & 15)) * 8)]);
        *reinterpret_cast<bf16x8*>(
            Vt + ((size_t)(b * D_ + d)) * S_ + t0 + cc * 8) = v8;
    }

    // ---- G half-partial: D[dp][d] = sum_t V[t][dp] K[t][d], t over 128 ----
    const int w = tid >> 6, l = tid & 63, g = l >> 4, n = l & 15;
    f32x4 acc[8];
    #pragma unroll
    for (int dc = 0; dc < 8; ++dc) acc[dc] = f32x4{0.f, 0.f, 0.f, 0.f};

    #pragma unroll
    for (int ki = 0; ki < 4; ++ki) {
        const int arow = 16 * w + n;              // wave's dp rows; row&15 == n
        const bf16x8 a = *reinterpret_cast<const bf16x8*>(
            &Vlds[arow * 128 + (((4 * ki + g) ^ n) * 8)]);
        #pragma unroll
        for (int dc = 0; dc < 8; ++dc) {
            int row = dc * 16 + n;
            const bf16x8 bb = *reinterpret_cast<const bf16x8*>(
                &Klds[row * 128 + (((4 * ki + g) ^ n) * 8)]);
            acc[dc] = __builtin_amdgcn_mfma_f32_16x16x32_bf16(a, bb, acc[dc], 0, 0, 0);
        }
    }

    unsigned short* out = P1h + (size_t)((b * NC + c) * 2 + half) * D_ * D_;
    #pragma unroll
    for (int dc = 0; dc < 8; ++dc)
        #pragma unroll
        for (int rr = 0; rr < 4; ++rr)
            out[(size_t)(16 * w + 4 * g + rr) * D_ + dc * 16 + n] = f2bf(acc[dc][rr]);
}

// ---------------------------------------------------------------------------
// prefix: exclusive prefix over bf16 half-partials (f32 accumulate);
//   single bf16 H. thread -> (b,dp,d), d = gid&127 -> coalesced.
// ---------------------------------------------------------------------------
__global__ __launch_bounds__(256) void prefix(const unsigned short* __restrict__ P1h,
                                              unsigned short* __restrict__ Hhi) {
    int gid = blockIdx.x * 256 + threadIdx.x;     // 0 .. 131071
    int d  = gid & 127;
    int dp = (gid >> 7) & 127;
    int b  = gid >> 14;
    float run = 0.f;
    #pragma unroll
    for (int c = 0; c < NC; ++c) {
        size_t hidx = ((size_t)(b * NC + c) * D_ + dp) * D_ + d;
        Hhi[hidx] = f2bf(run);
        size_t p = ((size_t)((b * NC + c) * 2) * D_ + dp) * D_ + d;
        run += bf2f(P1h[p]);
        run += bf2f(P1h[p + (size_t)D_ * D_]);
    }
}

// ---------------------------------------------------------------------------
// pass2 (r18: 256 blocks x 512 threads, 128 q-rows = 8 waves x 16 rows):
//   O = Q.H (inter) + causal(Q.K^T).V (intra). Q RoPE'd in-register from f32.
//   bid<128 -> half=1 (heavy, 4 intra tiles), else half=0 (2 tiles).
//   K/V double-buffered (64KB); counted-vmcnt: stage = 4 DMAs/thread ->
//   steady WAIT_VMCNT_4, final WAIT_VMCNT_0; stage(kt+2) after the bottom
//   barrier. Causal mask applied on every intra tile (covers waves whose
//   diagonal falls inside the 128-row group). Wave body = r4-verified math.
// ---------------------------------------------------------------------------
__global__ __launch_bounds__(512, 4) void pass2(const float* __restrict__ Q,
                                                const unsigned short* __restrict__ Kr,
                                                const unsigned short* __restrict__ Vt,
                                                const unsigned short* __restrict__ Hhi,
                                                float* __restrict__ Out) {
    __shared__ unsigned short Kb[2][64 * 128];    // [t][d] swizzled chunks, 2x16KB
    __shared__ unsigned short Vb[2][128 * 64];    // [d][t] swizzled chunks, 2x16KB

    const int bid  = blockIdx.x;
    const int half = (bid < 128) ? 1 : 0;         // heavy half first
    const int r2   = bid & 127;
    const int b    = r2 & 7;
    const int c    = r2 >> 3;                     // chunk 0..15
    const int c4   = c * 4;
    const int ppmax = 2 * half + 1;               // last intra tile index

    const int tid = threadIdx.x;
    const int wv = tid >> 6;                      // wave 0..7 (16 q-rows each)
    const int l  = tid & 63;
    const int g  = l >> 4;
    const int n  = l & 15;
    const int srow0 = c * 256 + half * 128 + wv * 16;   // wave's first q-row

    // ---- hoist Q with in-register RoPE: lane holds Q[s][d=32ks+8g+j] ----
    bf16x8 qf[4];
    {
        const int s = srow0 + n;
        const float* qp = Q + ((size_t)(b * S_ + s)) * D_ + 8 * g;
        float qv[4][8];
        #pragma unroll
        for (int ks = 0; ks < 4; ++ks) {
            *reinterpret_cast<float4*>(&qv[ks][0]) =
                *reinterpret_cast<const float4*>(qp + 32 * ks);
            *reinterpret_cast<float4*>(&qv[ks][4]) =
                *reinterpret_cast<const float4*>(qp + 32 * ks + 4);
        }
        unsigned short qb[4][8];
        #pragma unroll
        for (int hf = 0; hf < 2; ++hf)
            #pragma unroll
            for (int j = 0; j < 8; ++j) {
                int dm = 32 * hf + 8 * g + j;     // d mod 64
                float invf = exp2f(-0.20762050f * (float)dm);
                float ang = (float)s * invf;
                float sn, cs;
                __sincosf(ang, &sn, &cs);
                qb[hf][j]     = f2bf(qv[hf][j] * cs - qv[hf + 2][j] * sn);
                qb[hf + 2][j] = f2bf(qv[hf + 2][j] * cs + qv[hf][j] * sn);
            }
        #pragma unroll
        for (int ks = 0; ks < 4; ++ks) {
            bf16x8 f;
            #pragma unroll
            for (int j = 0; j < 8; ++j) f[j] = (short)qb[ks][j];
            qf[ks] = f;
        }
    }

    // K LDS chunk (t,cc) <- global chunk (t, cc^(t&15)); V chunk (d,cc) <- cc^(d&7)
    // 512 threads: 2 iters each => 4 vm entries per thread per stage
    auto stage = [&](int bufs, int tg) {
        const unsigned short* kbase = Kr + ((size_t)(b * S_ + tg * 64)) * D_;
        #pragma unroll
        for (int i = 0; i < 2; ++i) {
            int ci = i * 512 + tid;
            int t = ci >> 4, cc = ci & 15;
            load_lds16(kbase + t * D_ + ((cc ^ (t & 15)) * 8), &Kb[bufs][ci * 8]);
        }
        const unsigned short* vbase = Vt + (size_t)b * D_ * S_ + (size_t)tg * 64;
        #pragma unroll
        for (int i = 0; i < 2; ++i) {
            int ci = i * 512 + tid;
            int d = ci >> 3, cc = ci & 7;
            load_lds16(vbase + (size_t)d * S_ + ((cc ^ (d & 7)) * 8), &Vb[bufs][ci * 8]);
        }
    };

    f32x4 o[8];
    #pragma unroll
    for (int df = 0; df < 8; ++df) o[df] = f32x4{0.f, 0.f, 0.f, 0.f};

    stage(0, c4);                                  // tile 0 (4 entries)
    stage(1, c4 + 1);                              // tile 1 (8 outstanding)

    // ---- inter: O += Q . H (single bf16 H); DMAs fly underneath ----
    {
        const unsigned short* hbase = Hhi + (size_t)(b * NC + c) * D_ * D_;
        #pragma unroll
        for (int ks = 0; ks < 4; ++ks) {
            #pragma unroll
            for (int df = 0; df < 8; ++df) {
                const bf16x8 hh = *reinterpret_cast<const bf16x8*>(
                    hbase + (size_t)(df * 16 + n) * D_ + 32 * ks + 8 * g);
                o[df] = __builtin_amdgcn_mfma_f32_16x16x32_bf16(qf[ks], hh, o[df], 0, 0, 0);
            }
        }
    }

    // ---- intra: kt = 0..ppmax causal tiles, double-buffered counted-vmcnt ----
    for (int kt = 0; kt <= ppmax; ++kt) {
        if (kt < ppmax) { WAIT_VMCNT_4; }          // tile kt landed; kt+1 in flight
        else            { WAIT_VMCNT_0; }
        BARRIER;

        const int bufc = kt & 1;

        // E^T = K.Q^T (swapped): lane(g,n) holds E[t=tf*16+4g+rr][s=srow0+n]
        f32x4 e[4];
        #pragma unroll
        for (int tf = 0; tf < 4; ++tf) e[tf] = f32x4{0.f, 0.f, 0.f, 0.f};
        __builtin_amdgcn_s_setprio(1);
        #pragma unroll
        for (int tf = 0; tf < 4; ++tf) {
            #pragma unroll
            for (int ks = 0; ks < 4; ++ks) {
                const bf16x8 kf = *reinterpret_cast<const bf16x8*>(
                    &Kb[bufc][(tf * 16 + n) * 128 + (((4 * ks + g) ^ n) * 8)]);
                e[tf] = __builtin_amdgcn_mfma_f32_16x16x32_bf16(kf, qf[ks], e[tf], 0, 0, 0);
            }
        }
        __builtin_amdgcn_s_setprio(0);

        // causal mask — every intra tile (waves below this tile's diagonal
        // zero the whole tile; exact per-element condition)
        {
            int s_glob = srow0 + n;
            #pragma unroll
            for (int tf = 0; tf < 4; ++tf)
                #pragma unroll
                for (int rr = 0; rr < 4; ++rr) {
                    int t_glob = (c4 + kt) * 64 + tf * 16 + 4 * g + rr;
                    if (t_glob > s_glob) e[tf][rr] = 0.f;
                }
        }

        // E -> P A-frags in-register (8 cvt_pk + 8 permlane swaps, r4-verified)
        bf16x8 pf[2];
        {
            unsigned u0[4], u1[4];
            #pragma unroll
            for (int tf = 0; tf < 4; ++tf) {
                asm("v_cvt_pk_bf16_f32 %0, %1, %2"
                    : "=v"(u0[tf]) : "v"(e[tf][0]), "v"(e[tf][1]));
                asm("v_cvt_pk_bf16_f32 %0, %1, %2"
                    : "=v"(u1[tf]) : "v"(e[tf][2]), "v"(e[tf][3]));
            }
            #pragma unroll
            for (int ks = 0; ks < 2; ++ks) {
                unsigned a0 = u0[2 * ks], a1 = u0[2 * ks + 1];
                unsigned b0 = u1[2 * ks], b1 = u1[2 * ks + 1];
                asm("v_permlane32_swap_b32 %0, %1" : "+v"(a0), "+v"(a1));
                asm("v_permlane32_swap_b32 %0, %1" : "+v"(b0), "+v"(b1));
                asm("v_permlane16_swap_b32 %0, %1" : "+v"(a0), "+v"(a1));
                asm("v_permlane16_swap_b32 %0, %1" : "+v"(b0), "+v"(b1));
                pf[ks] = __builtin_bit_cast(bf16x8, u32x4{a0, b0, a1, b1});
            }
        }

        // O += P.V
        __builtin_amdgcn_s_setprio(1);
        #pragma unroll
        for (int df = 0; df < 8; ++df) {
            #pragma unroll
            for (int ks = 0; ks < 2; ++ks) {
                const bf16x8 vf = *reinterpret_cast<const bf16x8*>(
                    &Vb[bufc][(df * 16 + n) * 64 + (((4 * ks + g) ^ (n & 7)) * 8)]);
                o[df] = __builtin_amdgcn_mfma_f32_16x16x32_bf16(pf[ks], vf, o[df], 0, 0, 0);
            }
        }
        __builtin_amdgcn_s_setprio(0);

        BARRIER;                                   // all waves done reading bufc

        if (kt + 2 <= ppmax) stage(bufc, c4 + kt + 2);
    }

    // ---- epilogue: exclusive rows -> plain stores ----
    #pragma unroll
    for (int df = 0; df < 8; ++df)
        #pragma unroll
        for (int rr = 0; rr < 4; ++rr) {
            int srow = srow0 + 4 * g + rr;
            Out[((size_t)(b * S_ + srow)) * D_ + df * 16 + n] = o[df][rr];
        }
}

// ---------------------------------------------------------------------------
extern "C" void kernel_launch(void* const* d_in, const int* in_sizes, int n_in,
                              void* d_out, int out_size, void* d_ws, size_t ws_size,
                              hipStream_t stream) {
    const float* Q = (const float*)d_in[0];
    const float* K = (const float*)d_in[1];
    const float* V = (const float*)d_in[2];

    const size_t NE = (size_t)B_ * S_ * D_;       // 4.19M elems
    unsigned short* Kr  = (unsigned short*)d_ws;                   // 8 MB
    unsigned short* Vt  = Kr + NE;                                 // 8 MB
    unsigned short* P1h = Vt + NE;                                 // 8 MB bf16 (2 halves)
    unsigned short* Hhi = P1h + (size_t)B_ * NC * 2 * D_ * D_;     // 4 MB

    fusedA<<<256, 512, 0, stream>>>(K, V, Kr, Vt, P1h);
    prefix<<<512, 256, 0, stream>>>(P1h, Hhi);
    pass2 <<<256, 512, 0, stream>>>(Q, Kr, Vt, Hhi, (float*)d_out);
}